// Round 6
// baseline (643.351 us; speedup 1.0000x reference)
//
#include <hip/hip_runtime.h>
#include <cstdint>
#include <cstddef>

#define T_STEPS 50
#define B_SZ    1024
#define N_INP   784
#define H_SZ    256
#define L_SZ    10
#define M_TOT   (T_STEPS * B_SZ)   // 51200
#define NK0     26                 // K padded to 26*32 = 832
#define NSLICE  5                  // 5 balanced base-256 digits of rint(Wi*2^40): exact (|Wi|<0.5)

typedef int v4i  __attribute__((ext_vector_type(4)));
typedef int v16i __attribute__((ext_vector_type(16)));

// ---------------------------------------------------------------------------
// Phase 0a: transpose Wr[h][k] (256x256, fp32) -> WrT[k][h] for the scan.
// ---------------------------------------------------------------------------
__global__ __launch_bounds__(256) void transpose_wr(const float* __restrict__ Wr,
                                                    float* __restrict__ WrT) {
    __shared__ float tile[32][33];
    int bx = blockIdx.x * 32, by = blockIdx.y * 32;
    int tx = threadIdx.x % 32, ty = threadIdx.x / 32;   // 32 x 8
    #pragma unroll
    for (int j = 0; j < 32; j += 8)
        tile[ty + j][tx] = Wr[(size_t)(by + ty + j) * H_SZ + bx + tx];
    __syncthreads();
    #pragma unroll
    for (int j = 0; j < 32; j += 8)
        WrT[(size_t)(bx + ty + j) * H_SZ + by + tx] = tile[tx][ty + j];
}

// ---------------------------------------------------------------------------
// Phase 0b: Wi -> 5 balanced int8 digits of rint(Wi*2^40), fragment-linear:
// SBp[((nt*26+k0)*5+j)*1024 + lane*16 + byte]; h = nt*32+(lane&31),
// k = k0*32+(lane>>5)*16+byte.  (R5-verified exact, absmax 0.)
// ---------------------------------------------------------------------------
__global__ __launch_bounds__(128) void prep_packed(const float* __restrict__ Wi,
                                                   uint8_t* __restrict__ SBp) {
    const int nt   = blockIdx.x;
    const int k0   = blockIdx.y * 2 + (threadIdx.x >> 6);
    const int lane = threadIdx.x & 63;
    const int h    = nt * 32 + (lane & 31);
    const int g    = k0 * 2 + (lane >> 5);     // 16-float group index

    int wd[NSLICE][4] = {};
    #pragma unroll
    for (int u = 0; u < 16; ++u) {
        double wv = 0.0;
        if (g < 49) wv = (double)Wi[(size_t)h * N_INP + g * 16 + u];
        double r = rint(wv * 0x1p40);
        #pragma unroll
        for (int j = 0; j < NSLICE - 1; ++j) {
            double q  = floor((r + 128.0) * 0.00390625);
            double dj = r - 256.0 * q;                     // in [-128,127]
            wd[j][u >> 2] |= ((int)dj & 0xFF) << ((u & 3) * 8);
            r = q;
        }
        wd[NSLICE - 1][u >> 2] |= ((int)r & 0xFF) << ((u & 3) * 8);
    }
    uint8_t* base = SBp + ((size_t)(nt * NK0 + k0) * NSLICE) * 1024 + lane * 16;
    #pragma unroll
    for (int j = 0; j < NSLICE; ++j)
        *(v4i*)(base + (size_t)j * 1024) = (v4i){wd[j][0], wd[j][1], wd[j][2], wd[j][3]};
}

// ---------------------------------------------------------------------------
// Phase 0c: pack X (binary fp32) -> fragment-linear int8:
// Ap[(mt*26+k0)*1024 + lane*16 + byte]; m = mt*32+(lane&31),
// k = k0*32+(lane>>5)*16+byte; zero-pad k>=784. Writes perfectly coalesced.
// ---------------------------------------------------------------------------
__global__ __launch_bounds__(256) void pack_x(const float* __restrict__ X,
                                              uint8_t* __restrict__ Ap) {
    const int mt  = blockIdx.x;       // 1600
    const int tid = threadIdx.x;
    #pragma unroll
    for (int i = 0; i < 7; ++i) {
        int s = tid + i * 256;
        if (s < NK0 * 64) {
            int k0 = s >> 6, lane = s & 63;
            int m = mt * 32 + (lane & 31);
            int g = k0 * 2 + (lane >> 5);
            unsigned int bw[4] = {0u, 0u, 0u, 0u};
            if (g < 49) {
                const float* src = X + (size_t)m * N_INP + g * 16;
                #pragma unroll
                for (int q = 0; q < 4; ++q) {
                    float4 f = *(const float4*)(src + q * 4);
                    bw[q] = (f.x != 0.f ? 1u : 0u) | (f.y != 0.f ? 0x100u : 0u)
                          | (f.z != 0.f ? 0x10000u : 0u) | (f.w != 0.f ? 0x1000000u : 0u);
                }
            }
            *(v4i*)(Ap + ((size_t)(mt * NK0 + k0)) * 1024 + lane * 16) =
                (v4i){(int)bw[0], (int)bw[1], (int)bw[2], (int)bw[3]};
        }
    }
}

// ---------------------------------------------------------------------------
// Phase 1: cur = X @ Wi.T exactly via 5 int8-digit MFMAs. Block = 4 waves =
// 4 m-tiles; loop nt inside (A strips L1/L2-hot across nt). No LDS, no
// barriers, no register spill: a re-loaded per k0 (coalesced 16B/lane),
// acc[5] = 80 AGPRs. B fragment loads are coalesced 1KB from L2-hot SBp.
// ---------------------------------------------------------------------------
__global__ __launch_bounds__(256) void gemm_i8f(const uint8_t* __restrict__ Ap,
                                                const uint8_t* __restrict__ SBp,
                                                double* __restrict__ cur) {
    const int tid   = threadIdx.x;
    const int wave  = tid >> 6;
    const int lane  = tid & 63;
    const int ghalf = lane >> 5;
    const int mt    = blockIdx.x * 4 + wave;    // 1600 m-tiles

    const uint8_t* ap = Ap + (size_t)mt * NK0 * 1024 + lane * 16;

    for (int nt = 0; nt < 8; ++nt) {
        v16i acc[NSLICE] = {};
        const uint8_t* bp = SBp + ((size_t)nt * NK0 * NSLICE) * 1024 + lane * 16;

        for (int k0 = 0; k0 < NK0; ++k0) {
            v4i a = *(const v4i*)(ap + (size_t)k0 * 1024);
            #pragma unroll
            for (int j = 0; j < NSLICE; ++j) {
                v4i b = *(const v4i*)(bp + (size_t)(k0 * NSLICE + j) * 1024);
                acc[j] = __builtin_amdgcn_mfma_i32_32x32x32_i8(a, b, acc[j], 0, 0, 0);
            }
        }

        // recombine digits (exact integer Horner in fp64) and store
        const int h = nt * 32 + (lane & 31);
        #pragma unroll
        for (int r = 0; r < 16; ++r) {
            double s = (double)acc[4][r];
            s = s * 256.0 + (double)acc[3][r];
            s = s * 256.0 + (double)acc[2][r];
            s = s * 256.0 + (double)acc[1][r];
            s = s * 256.0 + (double)acc[0][r];
            int mr = mt * 32 + (r & 3) + 8 * (r >> 2) + 4 * ghalf;
            cur[(size_t)mr * H_SZ + h] = s * 0x1p-40;
        }
    }
}

// ---------------------------------------------------------------------------
// Phase 2: 50 LIF steps, fp64. One 64-thread wave per batch; thread owns 4
// neurons (float4 gathers from WrT). Ballot/list-build is intra-wave; one
// barrier per step (ping-pong list). Readout telescopes to spike counts.
// ---------------------------------------------------------------------------
__global__ __launch_bounds__(64) void snn_scan(const double* __restrict__ cur,
                                               const float* __restrict__ WrT,
                                               const float* __restrict__ Wout,
                                               const float* __restrict__ bout,
                                               float* __restrict__ out) {
    const int b    = blockIdx.x;
    const int lane = threadIdx.x;

    __shared__ int listS[2][H_SZ];
    __shared__ float cntS[H_SZ];

    double v[4]   = {0.0, 0.0, 0.0, 0.0};
    double syn[4] = {0.0, 0.0, 0.0, 0.0};
    int    cnt[4] = {0, 0, 0, 0};
    int    nn[2]  = {0, 0};

    const unsigned long long lt = (1ull << lane) - 1ull;
    const float4*  W4   = (const float4*)WrT;            // [k][64] float4
    const double*  curb = cur + (size_t)b * H_SZ + lane * 4;

    for (int t = 0; t < T_STEPS; ++t) {
        const int p = t & 1;

        // LIF dynamics (reference op order, fp64)
        bool z[4];
        #pragma unroll
        for (int q = 0; q < 4; ++q) {
            double vd = v[q] + 0.05 * ((0.0 - v[q]) + syn[q]);
            z[q] = vd > 0.5;
            v[q] = z[q] ? 0.0 : vd;
            cnt[q] += z[q] ? 1 : 0;
        }

        // gather recurrent drive from previous step's list (float4 rows)
        double rA[4] = {0, 0, 0, 0}, rB[4] = {0, 0, 0, 0};
        const int* Lp = listS[p];
        const int  np = nn[p];
        int j = 0;
        for (; j + 4 <= np; j += 4) {
            int k0 = Lp[j], k1 = Lp[j + 1], k2 = Lp[j + 2], k3 = Lp[j + 3];
            float4 w0 = W4[(size_t)k0 * 64 + lane];
            float4 w1 = W4[(size_t)k1 * 64 + lane];
            float4 w2 = W4[(size_t)k2 * 64 + lane];
            float4 w3 = W4[(size_t)k3 * 64 + lane];
            rA[0] += (double)w0.x + (double)w1.x;  rB[0] += (double)w2.x + (double)w3.x;
            rA[1] += (double)w0.y + (double)w1.y;  rB[1] += (double)w2.y + (double)w3.y;
            rA[2] += (double)w0.z + (double)w1.z;  rB[2] += (double)w2.z + (double)w3.z;
            rA[3] += (double)w0.w + (double)w1.w;  rB[3] += (double)w2.w + (double)w3.w;
        }
        for (; j < np; ++j) {
            float4 w = W4[(size_t)Lp[j] * 64 + lane];
            rA[0] += (double)w.x; rA[1] += (double)w.y;
            rA[2] += (double)w.z; rA[3] += (double)w.w;
        }

        // input drive
        const double* cr = curb + (size_t)t * B_SZ * H_SZ;
        double2 iA = *(const double2*)(cr);
        double2 iB = *(const double2*)(cr + 2);
        double inp[4] = {iA.x, iA.y, iB.x, iB.y};

        // publish new spike list (intra-wave: ballots + prefix popcounts)
        int* Lnew = listS[p ^ 1];
        int off = 0;
        #pragma unroll
        for (int q = 0; q < 4; ++q) {
            unsigned long long bal = __ballot((int)z[q]);
            if (z[q]) Lnew[off + __popcll(bal & lt)] = lane * 4 + q;
            off += (int)__popcll(bal);
        }
        nn[p ^ 1] = off;

        // synaptic update (reference order)
        #pragma unroll
        for (int q = 0; q < 4; ++q)
            syn[q] = (0.9 * syn[q] + inp[q]) + (rA[q] + rB[q]);

        __syncthreads();   // new list visible before next step's gather
    }

    #pragma unroll
    for (int q = 0; q < 4; ++q) cntS[lane * 4 + q] = (float)cnt[q];
    __syncthreads();
    if (lane < L_SZ) {
        double s = 0.0;
        for (int k = 0; k < H_SZ; ++k)
            s += (double)cntS[k] * (double)Wout[(size_t)lane * H_SZ + k];
        s += (double)T_STEPS * (double)bout[lane];
        out[(size_t)b * L_SZ + lane] = (float)(s / (double)T_STEPS);
    }
}

// ---------------------------------------------------------------------------
extern "C" void kernel_launch(void* const* d_in, const int* in_sizes, int n_in,
                              void* d_out, int out_size, void* d_ws, size_t ws_size,
                              hipStream_t stream) {
    const float* x    = (const float*)d_in[0];   // [50,1024,784]
    const float* Wi   = (const float*)d_in[1];   // [256,784]
    const float* Wr   = (const float*)d_in[2];   // [256,256]
    const float* Wout = (const float*)d_in[3];   // [10,256]
    const float* bout = (const float*)d_in[4];   // [10]
    float* out = (float*)d_out;                  // [1024,10]

    // ws layout (~148.8 MB; ws >= 642 MB per harness poison-fill WRITE_SIZE)
    char* ws = (char*)d_ws;
    double*  cur = (double*)(ws);                        // 104,857,600 B
    float*   WrT = (float*)(ws + 104857600);             //     262,144 B
    uint8_t* SBp = (uint8_t*)(ws + 105119744);           //   1,064,960 B
    uint8_t* Ap  = (uint8_t*)(ws + 106184704);           //  42,598,400 B

    hipLaunchKernelGGL(transpose_wr, dim3(8, 8), dim3(256), 0, stream, Wr, WrT);
    hipLaunchKernelGGL(prep_packed, dim3(8, 13), dim3(128), 0, stream, Wi, SBp);
    hipLaunchKernelGGL(pack_x, dim3(M_TOT / 32), dim3(256), 0, stream, x, Ap);
    hipLaunchKernelGGL(gemm_i8f, dim3(M_TOT / 128), dim3(256), 0, stream, Ap, SBp, cur);
    hipLaunchKernelGGL(snn_scan, dim3(B_SZ), dim3(64), 0, stream,
                       cur, WrT, Wout, bout, out);
}

// Round 7
// 404.296 us; speedup vs baseline: 1.5913x; 1.5913x over previous
//
#include <hip/hip_runtime.h>
#include <cstdint>
#include <cstddef>

#define T_STEPS 50
#define B_SZ    1024
#define N_INP   784
#define H_SZ    256
#define L_SZ    10
#define M_TOT   (T_STEPS * B_SZ)   // 51200
#define NK0     26                 // K padded to 26*32 = 832
#define NSLICE  5                  // 5 balanced base-256 digits of rint(Wi*2^40): exact (|Wi|<0.5)

typedef int v4i  __attribute__((ext_vector_type(4)));
typedef int v16i __attribute__((ext_vector_type(16)));

// ---------------------------------------------------------------------------
// Phase 0a: transpose Wr[h][k] (256x256, fp32) -> WrTz[k][h] (row 256 zeroed
// by hipMemsetAsync on the host side; dummy gather index hits it).
// ---------------------------------------------------------------------------
__global__ __launch_bounds__(256) void transpose_wr(const float* __restrict__ Wr,
                                                    float* __restrict__ WrTz) {
    __shared__ float tile[32][33];
    int bx = blockIdx.x * 32, by = blockIdx.y * 32;
    int tx = threadIdx.x % 32, ty = threadIdx.x / 32;   // 32 x 8
    #pragma unroll
    for (int j = 0; j < 32; j += 8)
        tile[ty + j][tx] = Wr[(size_t)(by + ty + j) * H_SZ + bx + tx];
    __syncthreads();
    #pragma unroll
    for (int j = 0; j < 32; j += 8)
        WrTz[(size_t)(bx + ty + j) * H_SZ + by + tx] = tile[tx][ty + j];
}

// ---------------------------------------------------------------------------
// Phase 0b: Wi -> 5 balanced int8 digits of rint(Wi*2^40), fragment-linear:
// SBp[((nt*26+k0)*5+j)*1024 + lane*16 + byte]; h = nt*32+(lane&31),
// k = k0*32+(lane>>5)*16+byte.  (R5/R6-verified exact, absmax 0.)
// ---------------------------------------------------------------------------
__global__ __launch_bounds__(128) void prep_packed(const float* __restrict__ Wi,
                                                   uint8_t* __restrict__ SBp) {
    const int nt   = blockIdx.x;
    const int k0   = blockIdx.y * 2 + (threadIdx.x >> 6);
    const int lane = threadIdx.x & 63;
    const int h    = nt * 32 + (lane & 31);
    const int g    = k0 * 2 + (lane >> 5);     // 16-float group index

    int wd[NSLICE][4] = {};
    #pragma unroll
    for (int u = 0; u < 16; ++u) {
        double wv = 0.0;
        if (g < 49) wv = (double)Wi[(size_t)h * N_INP + g * 16 + u];
        double r = rint(wv * 0x1p40);
        #pragma unroll
        for (int j = 0; j < NSLICE - 1; ++j) {
            double q  = floor((r + 128.0) * 0.00390625);
            double dj = r - 256.0 * q;                     // in [-128,127]
            wd[j][u >> 2] |= ((int)dj & 0xFF) << ((u & 3) * 8);
            r = q;
        }
        wd[NSLICE - 1][u >> 2] |= ((int)r & 0xFF) << ((u & 3) * 8);
    }
    uint8_t* base = SBp + ((size_t)(nt * NK0 + k0) * NSLICE) * 1024 + lane * 16;
    #pragma unroll
    for (int j = 0; j < NSLICE; ++j)
        *(v4i*)(base + (size_t)j * 1024) = (v4i){wd[j][0], wd[j][1], wd[j][2], wd[j][3]};
}

// ---------------------------------------------------------------------------
// Phase 0c: pack X (binary fp32) -> fragment-linear int8 (R6-verified).
// Ap[(mt*26+k0)*1024 + lane*16 + byte]
// ---------------------------------------------------------------------------
__global__ __launch_bounds__(256) void pack_x(const float* __restrict__ X,
                                              uint8_t* __restrict__ Ap) {
    const int mt  = blockIdx.x;       // 1600
    const int tid = threadIdx.x;
    #pragma unroll
    for (int i = 0; i < 7; ++i) {
        int s = tid + i * 256;
        if (s < NK0 * 64) {
            int k0 = s >> 6, lane = s & 63;
            int m = mt * 32 + (lane & 31);
            int g = k0 * 2 + (lane >> 5);
            unsigned int bw[4] = {0u, 0u, 0u, 0u};
            if (g < 49) {
                const float* src = X + (size_t)m * N_INP + g * 16;
                #pragma unroll
                for (int q = 0; q < 4; ++q) {
                    float4 f = *(const float4*)(src + q * 4);
                    bw[q] = (f.x != 0.f ? 1u : 0u) | (f.y != 0.f ? 0x100u : 0u)
                          | (f.z != 0.f ? 0x10000u : 0u) | (f.w != 0.f ? 0x1000000u : 0u);
                }
            }
            *(v4i*)(Ap + ((size_t)(mt * NK0 + k0)) * 1024 + lane * 16) =
                (v4i){(int)bw[0], (int)bw[1], (int)bw[2], (int)bw[3]};
        }
    }
}

// ---------------------------------------------------------------------------
// Phase 1: cur = X @ Wi.T exactly via 5 int8-digit MFMAs.
// Block = 256 thr = 4 waves; each wave owns TWO m-tiles (B fragment reused
// for 2 MFMAs per ds_read -> B LDS traffic halved). Block covers 8 m-tiles,
// one nt. B staged per k0-pair (10 KB) into double-buffered LDS; one barrier
// per pair. A fragments read from L2/L3 (pre-packed), prefetched one pair
// ahead. Grid 200 x 8 = 1600 blocks (>=2 blocks/CU).
// ---------------------------------------------------------------------------
__global__ __launch_bounds__(256) void gemm_i8s(const uint8_t* __restrict__ Ap,
                                                const uint8_t* __restrict__ SBp,
                                                double* __restrict__ cur) {
    __shared__ __align__(16) uint8_t Bs[2][2 * NSLICE * 1024];   // 2 x 10 KB

    const int tid   = threadIdx.x;
    const int wave  = tid >> 6;
    const int lane  = tid & 63;
    const int ghalf = lane >> 5;
    const int nt    = blockIdx.y;
    const int mt0   = (blockIdx.x * 4 + wave) * 2;     // wave owns mt0, mt0+1
    const int mt1   = mt0 + 1;

    const uint8_t* ap0 = Ap + (size_t)mt0 * NK0 * 1024 + lane * 16;
    const uint8_t* ap1 = Ap + (size_t)mt1 * NK0 * 1024 + lane * 16;
    const uint8_t* bbase = SBp + ((size_t)nt * NK0 * NSLICE) * 1024;

    // stage pair 0 and prefetch A pair 0
    {
        const uint8_t* src = bbase;
        #pragma unroll
        for (int i = 0; i < 2; ++i) {
            int s = tid + i * 256;
            *(v4i*)(Bs[0] + s * 16) = *(const v4i*)(src + s * 16);
        }
        if (tid < 128) {
            int s = tid + 512;
            *(v4i*)(Bs[0] + s * 16) = *(const v4i*)(src + s * 16);
        }
    }
    v4i a0c = *(const v4i*)(ap0);
    v4i a0n = *(const v4i*)(ap0 + 1024);
    v4i a1c = *(const v4i*)(ap1);
    v4i a1n = *(const v4i*)(ap1 + 1024);
    __syncthreads();

    v16i acc0[NSLICE] = {};
    v16i acc1[NSLICE] = {};

    for (int p = 0; p < 13; ++p) {
        const int cb = p & 1;
        v4i b0c = a0c, b0n = a0n, b1c = a1c, b1n = a1n;
        if (p < 12) {
            // stage next pair into the other buffer + prefetch next A pair
            const uint8_t* src = bbase + (size_t)(p + 1) * 2 * NSLICE * 1024;
            uint8_t* dst = Bs[cb ^ 1];
            #pragma unroll
            for (int i = 0; i < 2; ++i) {
                int s = tid + i * 256;
                *(v4i*)(dst + s * 16) = *(const v4i*)(src + s * 16);
            }
            if (tid < 128) {
                int s = tid + 512;
                *(v4i*)(dst + s * 16) = *(const v4i*)(src + s * 16);
            }
            a0c = *(const v4i*)(ap0 + (size_t)(2 * p + 2) * 1024);
            a0n = *(const v4i*)(ap0 + (size_t)(2 * p + 3) * 1024);
            a1c = *(const v4i*)(ap1 + (size_t)(2 * p + 2) * 1024);
            a1n = *(const v4i*)(ap1 + (size_t)(2 * p + 3) * 1024);
        }
        #pragma unroll
        for (int dk = 0; dk < 2; ++dk) {
            v4i aa0 = dk ? b0n : b0c;
            v4i aa1 = dk ? b1n : b1c;
            #pragma unroll
            for (int j = 0; j < NSLICE; ++j) {
                v4i b = *(const v4i*)(Bs[cb] + (dk * NSLICE + j) * 1024 + lane * 16);
                acc0[j] = __builtin_amdgcn_mfma_i32_32x32x32_i8(aa0, b, acc0[j], 0, 0, 0);
                acc1[j] = __builtin_amdgcn_mfma_i32_32x32x32_i8(aa1, b, acc1[j], 0, 0, 0);
            }
        }
        __syncthreads();
    }

    // recombine digits (exact integer Horner in fp64) and store both m-tiles
    const int h = nt * 32 + (lane & 31);
    #pragma unroll
    for (int r = 0; r < 16; ++r) {
        int mloc = (r & 3) + 8 * (r >> 2) + 4 * ghalf;
        double s0 = (double)acc0[4][r];
        s0 = s0 * 256.0 + (double)acc0[3][r];
        s0 = s0 * 256.0 + (double)acc0[2][r];
        s0 = s0 * 256.0 + (double)acc0[1][r];
        s0 = s0 * 256.0 + (double)acc0[0][r];
        cur[(size_t)(mt0 * 32 + mloc) * H_SZ + h] = s0 * 0x1p-40;
        double s1 = (double)acc1[4][r];
        s1 = s1 * 256.0 + (double)acc1[3][r];
        s1 = s1 * 256.0 + (double)acc1[2][r];
        s1 = s1 * 256.0 + (double)acc1[1][r];
        s1 = s1 * 256.0 + (double)acc1[0][r];
        cur[(size_t)(mt1 * 32 + mloc) * H_SZ + h] = s1 * 0x1p-40;
    }
}

// ---------------------------------------------------------------------------
// Phase 2: 50 LIF steps fp64, block = batch (256 thr = 4 waves, 16 waves/CU).
// Next-step inp prefetched (hides HBM latency). Spike list padded to x8 with
// dummy index 256 -> zero row of WrTz: gather is fixed-unroll-8 independent
// loads (one latency exposure per 8 rows). All threads derive the list count
// locally from the shared ballot masks (no count round-trip).
// ---------------------------------------------------------------------------
__device__ __forceinline__ int build_list_pad(const unsigned long long* zm, int h,
                                              int* list) {
    unsigned long long w0 = zm[0], w1 = zm[1], w2 = zm[2], w3 = zm[3];
    int c0 = __popcll(w0), c1 = __popcll(w1), c2 = __popcll(w2), c3 = __popcll(w3);
    int wi = h >> 6;
    unsigned long long word = zm[wi];
    int base = (wi > 0 ? c0 : 0) + (wi > 1 ? c1 : 0) + (wi > 2 ? c2 : 0);
    int bit = h & 63;
    bool act = (word >> bit) & 1ull;
    int pos = __popcll(word & ((1ull << bit) - 1ull));
    if (act) list[base + pos] = h;
    int tot = c0 + c1 + c2 + c3;
    if (h < 8) list[tot + h] = 256;          // pad with zero-row index
    return tot;
}

__global__ __launch_bounds__(256) void snn_scan(const double* __restrict__ cur,
                                                const float* __restrict__ WrTz,
                                                const float* __restrict__ Wout,
                                                const float* __restrict__ bout,
                                                float* __restrict__ out) {
    const int b = blockIdx.x;
    const int h = threadIdx.x;

    __shared__ unsigned long long zmS[4];
    __shared__ int listS[2][H_SZ + 8];
    __shared__ float cntS[H_SZ];

    double v = 0.0, syn = 0.0;
    int cnt = 0;
    int nn[2] = {0, 0};

    const double* curb = cur + (size_t)b * H_SZ + h;
    const float*  wrh  = WrTz + h;
    double inp_c = curb[0];                   // prefetch t=0

    for (int t = 0; t < T_STEPS; ++t) {
        const int p = t & 1;
        // prefetch next step's input drive (full step of slack)
        int tn = (t < T_STEPS - 1) ? t + 1 : t;
        double inp_n = curb[(size_t)tn * B_SZ * H_SZ];

        // LIF dynamics, reference op order, fp64
        double v_dec = v + 0.05 * ((0.0 - v) + syn);
        double i_dec = 0.9 * syn;
        bool   z_new = v_dec > 0.5;
        v = z_new ? 0.0 : v_dec;
        cnt += z_new ? 1 : 0;

        // gather recurrent drive: unroll-8 batches of independent loads
        double r0 = 0.0, r1 = 0.0, r2 = 0.0, r3 = 0.0;
        const int* lp = listS[p];
        const int  n  = nn[p];
        for (int j = 0; j < n; j += 8) {
            float f0 = wrh[(size_t)lp[j + 0] * H_SZ];
            float f1 = wrh[(size_t)lp[j + 1] * H_SZ];
            float f2 = wrh[(size_t)lp[j + 2] * H_SZ];
            float f3 = wrh[(size_t)lp[j + 3] * H_SZ];
            float f4 = wrh[(size_t)lp[j + 4] * H_SZ];
            float f5 = wrh[(size_t)lp[j + 5] * H_SZ];
            float f6 = wrh[(size_t)lp[j + 6] * H_SZ];
            float f7 = wrh[(size_t)lp[j + 7] * H_SZ];
            r0 += (double)f0 + (double)f1;
            r1 += (double)f2 + (double)f3;
            r2 += (double)f4 + (double)f5;
            r3 += (double)f6 + (double)f7;
        }

        // publish new spike mask
        unsigned long long bal = __ballot((int)z_new);
        if ((h & 63) == 0) zmS[h >> 6] = bal;
        __syncthreads();                       // masks visible (and prior list reads done)
        nn[p ^ 1] = build_list_pad(zmS, h, listS[p ^ 1]);
        syn = (i_dec + inp_c) + ((r0 + r1) + (r2 + r3));
        inp_c = inp_n;
        __syncthreads();                       // new list complete
    }

    cntS[h] = (float)cnt;
    __syncthreads();
    if (h < L_SZ) {
        double s = 0.0;
        for (int k = 0; k < H_SZ; ++k)
            s += (double)cntS[k] * (double)Wout[(size_t)h * H_SZ + k];
        s += (double)T_STEPS * (double)bout[h];
        out[(size_t)b * L_SZ + h] = (float)(s / (double)T_STEPS);
    }
}

// ---------------------------------------------------------------------------
extern "C" void kernel_launch(void* const* d_in, const int* in_sizes, int n_in,
                              void* d_out, int out_size, void* d_ws, size_t ws_size,
                              hipStream_t stream) {
    const float* x    = (const float*)d_in[0];   // [50,1024,784]
    const float* Wi   = (const float*)d_in[1];   // [256,784]
    const float* Wr   = (const float*)d_in[2];   // [256,256]
    const float* Wout = (const float*)d_in[3];   // [10,256]
    const float* bout = (const float*)d_in[4];   // [10]
    float* out = (float*)d_out;                  // [1024,10]

    // ws layout (~148.8 MB; ws >= 642 MB per harness poison-fill WRITE_SIZE)
    char* ws = (char*)d_ws;
    double*  cur  = (double*)(ws);                       // 104,857,600 B
    float*   WrTz = (float*)(ws + 104857600);            // 257 rows x 256 x 4 = 263,168 B
    uint8_t* SBp  = (uint8_t*)(ws + 105121792);          //   1,064,960 B
    uint8_t* Ap   = (uint8_t*)(ws + 106186752);          //  42,598,400 B

    hipMemsetAsync(WrTz + 256 * H_SZ, 0, H_SZ * sizeof(float), stream);  // zero row
    hipLaunchKernelGGL(transpose_wr, dim3(8, 8), dim3(256), 0, stream, Wr, WrTz);
    hipLaunchKernelGGL(prep_packed, dim3(8, 13), dim3(128), 0, stream, Wi, SBp);
    hipLaunchKernelGGL(pack_x, dim3(M_TOT / 32), dim3(256), 0, stream, x, Ap);
    hipLaunchKernelGGL(gemm_i8s, dim3(M_TOT / 256, 8), dim3(256), 0, stream, Ap, SBp, cur);
    hipLaunchKernelGGL(snn_scan, dim3(B_SZ), dim3(256), 0, stream,
                       cur, WrTz, Wout, bout, out);
}